// Round 3
// baseline (84.041 us; speedup 1.0000x reference)
//
#include <hip/hip_runtime.h>
#include <cstdint>

namespace {
constexpr int kG = 262144;                    // 64^3 cells
constexpr int kB = 2;
constexpr int kN = 8192;
constexpr int kPts = kB * kN;                 // 16384 points
constexpr float kDX = 1.0f / 64.0f;
constexpr float kRad2 = 0.00152587890625f;    // (2.5/64)^2, exact
constexpr float kInvRad = 25.6f;              // 1/RADIUS (1-2 ulp vs divide)
constexpr float kEps = 1e-12f;
constexpr float kFourOverPi = 1.27323954473516268615f;

constexpr int PPB = 4;                        // points per block (1 wave each)
constexpr int THREADS = PPB * 64;             // 256
constexpr int MAXREC = 88;                    // nv<=81, pad to 84, prefetch to 87
constexpr int SLOT = 16;                      // floats per record (4 x float4)
constexpr int GSTRIDE = MAXREC * SLOT + 4;    // floats per point region
}

__device__ __forceinline__ float sgnf(float v) {
    return (v > 0.f) ? 1.f : ((v < 0.f) ? -1.f : 0.f);
}

// ---- transpose [B][C][G] -> [B][G][C] so per-cell channel gathers are one 64B line ----
__global__ __launch_bounds__(256) void transpose_feat_k(const float* __restrict__ in,
                                                        float* __restrict__ feat) {
    int idx = blockIdx.x * 256 + threadIdx.x;      // over B*G
    if (idx >= kB * kG) return;
    int b = idx >> 18;
    int g = idx & (kG - 1);
    float v[16];
#pragma unroll
    for (int c = 0; c < 16; ++c) v[c] = in[((size_t)(b * 16 + c)) * kG + g];
    float4* dst = reinterpret_cast<float4*>(feat + (size_t)idx * 16);
    dst[0] = make_float4(v[0], v[1], v[2], v[3]);
    dst[1] = make_float4(v[4], v[5], v[6], v[7]);
    dst[2] = make_float4(v[8], v[9], v[10], v[11]);
    dst[3] = make_float4(v[12], v[13], v[14], v[15]);
}

__global__ __launch_bounds__(THREADS) void cconv_main(
    const float* __restrict__ input, const float* __restrict__ pos,
    const float* __restrict__ W, const float* __restrict__ feat,
    float* __restrict__ out, int use_feat)
{
    // each wave (point) touches only its own region; same-wave DS ops are ordered
    // -> no __syncthreads needed, waves run fully decoupled.
    __shared__ __align__(16) float rec[PPB * GSTRIDE];

    const int tid = threadIdx.x;
    const int wv = tid >> 6;            // point-in-block (one wave per point)
    const int lane = tid & 63;
    const int sg = lane >> 4;           // sub-group 0..3
    const int lig = lane & 15;          // channel lane within sub-group
    const int pt = blockIdx.x * PPB + wv;
    const int b = pt >> 13;             // / kN

    const float px = pos[pt * 3 + 0];
    const float py = pos[pt * 3 + 1];
    const float pz = pos[pt * 3 + 2];
    const int bx = (int)floorf(px * 64.f);
    const int by = (int)floorf(py * 64.f);
    const int bz = (int)floorf(pz * 64.f);

    float* grec = rec + wv * GSTRIDE;
    int nv = 0;

    // ---- pass 1a: validity over 216 candidates, full-wave ballot-compact ----
#pragma unroll
    for (int it = 0; it < 4; ++it) {
        int k = it * 64 + lane;
        bool valid = false;
        float rx = 0.f, ry = 0.f, rz = 0.f;
        int flat = 0;
        if (k < 216) {
            int a = k / 36;
            int r = k - a * 36;
            int b1 = r / 6;
            int c1 = r - b1 * 6;
            int g0 = bx + a - 2, g1 = by + b1 - 2, g2 = bz + c1 - 2;
            bool inb = (g0 >= 0) & (g0 < 64) & (g1 >= 0) & (g1 < 64) &
                       (g2 >= 0) & (g2 < 64);
            int q0 = min(max(g0, 0), 63);
            int q1 = min(max(g1, 0), 63);
            int q2 = min(max(g2, 0), 63);
            flat = (q0 * 64 + q1) * 64 + q2;
            // grid_pos[i] == i*DX exactly -> compute, don't load
            rx = __fsub_rn((float)q0 * kDX, px);
            ry = __fsub_rn((float)q1 * kDX, py);
            rz = __fsub_rn((float)q2 * kDX, pz);
            // forbid fma-contraction so the <= compare matches XLA mul-then-add
            float d2 = __fadd_rn(__fadd_rn(__fmul_rn(rx, rx), __fmul_rn(ry, ry)),
                                 __fmul_rn(rz, rz));
            valid = inb && (d2 <= kRad2);
        }
        unsigned long long ball = __ballot(valid);
        if (valid) {
            int slot = nv + __popcll(ball & ((1ull << lane) - 1ull));
            *reinterpret_cast<float4*>(grec + slot * SLOT) =
                make_float4(rx, ry, rz, __int_as_float(flat));
        }
        nv += (int)__popcll(ball);
    }
    __builtin_amdgcn_wave_barrier();

    // ---- zero pad records [nv, nv+8) so pass 2 runs branch-free with prefetch ----
    if (lane < 8 && nv + lane < MAXREC) {
        float4 z = make_float4(0.f, 0.f, 0.f, 0.f);
        float4* zp = reinterpret_cast<float4*>(grec + (nv + lane) * SLOT);
        zp[0] = z; zp[1] = z; zp[2] = z; zp[3] = z;
    }

    // ---- pass 1b: mapping + hat weights; store 9 xy-products + 3 z-weights ----
    for (int s = lane; s < nv; s += 64) {
        float* rp = grec + s * SLOT;
        float4 rc = *reinterpret_cast<const float4*>(rp);
        float flat_bits = rc.w;
        float ux = rc.x * kInvRad, uy = rc.y * kInvRad, uz = rc.z * kInvRad;

        // sphere -> cylinder (branch-free, HW rcp/rsq/sqrt: ~1ulp)
        float xx = ux * ux, yy = uy * uy, zz = uz * uz;
        float xy2 = xx + yy;
        float sq = xy2 + zz;
        float nrm = __builtin_amdgcn_sqrtf(fmaxf(sq, kEps));
        bool cap = (1.25f * zz > xy2);
        float scap = __builtin_amdgcn_sqrtf(3.f * nrm) *
                     __builtin_amdgcn_rsqf(nrm + fabsf(uz) + kEps);
        float sside = nrm * __builtin_amdgcn_rsqf(fmaxf(xy2, kEps));
        float sc = cap ? scap : sside;
        float xc = ux * sc, yc = uy * sc;
        float zc = cap ? sgnf(uz) * nrm : 1.5f * uz;
        bool z1 = (sq <= kEps);
        if (z1) { xc = 0.f; yc = 0.f; zc = 0.f; }

        // cylinder -> cube (single atan poly path)
        float xy2b = xc * xc + yc * yc;
        float nxy = __builtin_amdgcn_sqrtf(fmaxf(xy2b, kEps));
        bool xdom = (fabsf(yc) <= fabsf(xc));
        float num = xdom ? yc : xc;
        float den = xdom ? xc : yc;
        float dsafe = (fabsf(den) > kEps) ? den : 1.0f;
        float r = num * __builtin_amdgcn_rcpf(dsafe);     // |r| <= 1
        float r2 = r * r;
        float at = -0.01172120f;
        at = at * r2 + 0.05265332f;
        at = at * r2 - 0.11643287f;
        at = at * r2 + 0.19354346f;
        at = at * r2 - 0.33262347f;
        at = at * r2 + 0.99997726f;
        at = at * r;                                      // ~atan(r), err ~1e-5
        float tt = sgnf(den) * nxy;
        float g = tt * kFourOverPi * at;
        float xo = xdom ? tt : g;
        float yo = xdom ? g : tt;
        if (xy2b <= kEps) { xo = 0.f; yo = 0.f; }
        float zo = zc;

        // hat weights: c = clamp(v+1, 0, 2) (== ref's (v*0.5+0.5)*2 exactly)
        float tx = fminf(fmaxf(xo + 1.f, 0.f), 2.f) - 1.f;
        float ty = fminf(fmaxf(yo + 1.f, 0.f), 2.f) - 1.f;
        float tz = fminf(fmaxf(zo + 1.f, 0.f), 2.f) - 1.f;
        float wx0 = fmaxf(0.f, -tx), wx1 = 1.f - fabsf(tx), wx2 = fmaxf(0.f, tx);
        float wy0 = fmaxf(0.f, -ty), wy1 = 1.f - fabsf(ty), wy2 = fmaxf(0.f, ty);
        float wz0 = fmaxf(0.f, -tz), wz1 = 1.f - fabsf(tz), wz2 = fmaxf(0.f, tz);

        float4* rp4 = reinterpret_cast<float4*>(rp);
        rp4[0] = make_float4(wx0 * wy0, wx0 * wy1, wx0 * wy2, wz0);
        rp4[1] = make_float4(wx1 * wy0, wx1 * wy1, wx1 * wy2, wz1);
        rp4[2] = make_float4(wx2 * wy0, wx2 * wy1, wx2 * wy2, wz2);
        rp[12] = flat_bits;
    }
    __builtin_amdgcn_wave_barrier();

    // ---- pass 2: sub-group sg takes records sg, sg+4, ...; 30 VALU/record ----
    float acc[28];
#pragma unroll
    for (int t = 0; t < 28; ++t) acc[t] = 0.f;

    const float* fbp = use_feat ? (feat + (size_t)b * kG * 16)
                                : (input + (size_t)b * 16 * kG);
    const int nvp = (nv + 3) & ~3;

    const float* rp = grec + sg * SLOT;
    float4 F0 = reinterpret_cast<const float4*>(rp)[0];
    float4 F1 = reinterpret_cast<const float4*>(rp)[1];
    float4 F2 = reinterpret_cast<const float4*>(rp)[2];
    int flat = __float_as_int(rp[12]);
    float f = use_feat ? fbp[(size_t)flat * 16 + lig] : fbp[(size_t)lig * kG + flat];

    for (int s = sg; s < nvp; s += 4) {
        const float* rpn = rp + 4 * SLOT;
        float4 G0 = reinterpret_cast<const float4*>(rpn)[0];
        float4 G1 = reinterpret_cast<const float4*>(rpn)[1];
        float4 G2 = reinterpret_cast<const float4*>(rpn)[2];
        int flatn = __float_as_int(rpn[12]);
        float fn = use_feat ? fbp[(size_t)flatn * 16 + lig]
                            : fbp[(size_t)lig * kG + flatn];
        float m0 = F0.w * f, m1 = F1.w * f, m2 = F2.w * f;
        acc[0]  += F0.x * m0; acc[1]  += F0.x * m1; acc[2]  += F0.x * m2;
        acc[3]  += F0.y * m0; acc[4]  += F0.y * m1; acc[5]  += F0.y * m2;
        acc[6]  += F0.z * m0; acc[7]  += F0.z * m1; acc[8]  += F0.z * m2;
        acc[9]  += F1.x * m0; acc[10] += F1.x * m1; acc[11] += F1.x * m2;
        acc[12] += F1.y * m0; acc[13] += F1.y * m1; acc[14] += F1.y * m2;
        acc[15] += F1.z * m0; acc[16] += F1.z * m1; acc[17] += F1.z * m2;
        acc[18] += F2.x * m0; acc[19] += F2.x * m1; acc[20] += F2.x * m2;
        acc[21] += F2.y * m0; acc[22] += F2.y * m1; acc[23] += F2.y * m2;
        acc[24] += F2.z * m0; acc[25] += F2.z * m1; acc[26] += F2.z * m2;
        F0 = G0; F1 = G1; F2 = G2; f = fn; rp = rpn;
    }

    // ---- fold-reduce acc over sub-groups: sg ends with taps [7sg, 7sg+7) ----
    const bool hi32 = (lane >= 32);
    float kp[14];
#pragma unroll
    for (int j = 0; j < 14; ++j) {
        float send = hi32 ? acc[j] : acc[14 + j];
        float recv = __shfl_xor(send, 32);
        kp[j] = (hi32 ? acc[14 + j] : acc[j]) + recv;
    }
    const bool hi16 = (lane & 16) != 0;
    float kk[7];
#pragma unroll
    for (int j = 0; j < 7; ++j) {
        float send = hi16 ? kp[j] : kp[7 + j];
        float recv = __shfl_xor(send, 16);
        kk[j] = (hi16 ? kp[7 + j] : kp[j]) + recv;
    }

    // ---- pass 3: taps t = 7sg+j; partial[d] += kk[j] * W[t][lig][d] ----
    float partial[16];
#pragma unroll
    for (int d = 0; d < 16; ++d) partial[d] = 0.f;
    const float* wbase = W + (sg * 7) * 256 + lig * 16;
#pragma unroll
    for (int j = 0; j < 7; ++j) {
        if (sg * 7 + j < 27) {          // sg3,j6 is the pad tap
            const float4* wr = reinterpret_cast<const float4*>(wbase + j * 256);
            float4 a0 = wr[0], a1 = wr[1], a2 = wr[2], a3 = wr[3];
            float at_ = kk[j];
            partial[0]  += at_ * a0.x; partial[1]  += at_ * a0.y;
            partial[2]  += at_ * a0.z; partial[3]  += at_ * a0.w;
            partial[4]  += at_ * a1.x; partial[5]  += at_ * a1.y;
            partial[6]  += at_ * a1.z; partial[7]  += at_ * a1.w;
            partial[8]  += at_ * a2.x; partial[9]  += at_ * a2.y;
            partial[10] += at_ * a2.z; partial[11] += at_ * a2.w;
            partial[12] += at_ * a3.x; partial[13] += at_ * a3.y;
            partial[14] += at_ * a3.z; partial[15] += at_ * a3.w;
        }
    }

    // ---- fold-reduce 16 partials across the 16-lane group: lane lig ends with d=lig ----
#pragma unroll
    for (int half = 8; half >= 1; half >>= 1) {
        bool up = (lig & half) != 0;
#pragma unroll
        for (int j = 0; j < half; ++j) {
            float send = up ? partial[j] : partial[j + half];
            float recv = __shfl_xor(send, half);
            partial[j] = (up ? partial[j + half] : partial[j]) + recv;
        }
    }
    float res = partial[0];
    res += __shfl_xor(res, 16);
    res += __shfl_xor(res, 32);
    res = res / fmaxf((float)nv, 1.f);
    if (lane < 16) out[(size_t)pt * 16 + lig] = res;
}

extern "C" void kernel_launch(void* const* d_in, const int* in_sizes, int n_in,
                              void* d_out, int out_size, void* d_ws, size_t ws_size,
                              hipStream_t stream) {
    const float* input = (const float*)d_in[0];   // [2,16,64,64,64]
    const float* pos   = (const float*)d_in[1];   // [2,8192,3]
    const float* W     = (const float*)d_in[2];   // [3,3,3,16,16]
    // d_in[3] grid_pos unused: grid_pos[i] == i*DX exactly
    float* out  = (float*)d_out;
    float* feat = (float*)d_ws;

    const size_t feat_bytes = (size_t)kB * kG * 16 * sizeof(float);
    int use_feat = (d_ws != nullptr && ws_size >= feat_bytes) ? 1 : 0;

    if (use_feat) {
        transpose_feat_k<<<(kB * kG + 255) / 256, 256, 0, stream>>>(input, feat);
    }
    cconv_main<<<kPts / PPB, THREADS, 0, stream>>>(input, pos, W, feat, out, use_feat);
}

// Round 4
// 79.617 us; speedup vs baseline: 1.0556x; 1.0556x over previous
//
#include <hip/hip_runtime.h>
#include <cstdint>

namespace {
constexpr int kG = 262144;                    // 64^3 cells
constexpr int kB = 2;
constexpr int kN = 8192;
constexpr int kPts = kB * kN;                 // 16384 points
constexpr float kDX = 1.0f / 64.0f;
constexpr float kRad2 = 0.00152587890625f;    // (2.5/64)^2, exact
constexpr float kInvRad = 25.6f;              // 1/RADIUS
constexpr float kEps = 1e-12f;
constexpr float kFourOverPi = 1.27323954473516268615f;

constexpr int PPB = 4;                        // points per block (1 wave each)
constexpr int THREADS = PPB * 64;             // 256
constexpr int MAXREC = 88;                    // nv<=81, +pad/prefetch
constexpr int SLOT = 12;                      // floats/record: stride 48B cycles 8 bank-quads
constexpr int NFLAT = 108;                    // compact flat-index array
constexpr int GSTRIDE = MAXREC * SLOT + NFLAT + 4;   // 1168 floats per point region
}

__device__ __forceinline__ float sgnf(float v) {
    return (v > 0.f) ? 1.f : ((v < 0.f) ? -1.f : 0.f);
}

// ---- transpose [B][C][G] -> [B][G][C] so per-cell channel gathers are one 64B line ----
__global__ __launch_bounds__(256) void transpose_feat_k(const float* __restrict__ in,
                                                        float* __restrict__ feat) {
    int idx = blockIdx.x * 256 + threadIdx.x;      // over B*G
    if (idx >= kB * kG) return;
    int b = idx >> 18;
    int g = idx & (kG - 1);
    float v[16];
#pragma unroll
    for (int c = 0; c < 16; ++c) v[c] = in[((size_t)(b * 16 + c)) * kG + g];
    float4* dst = reinterpret_cast<float4*>(feat + (size_t)idx * 16);
    dst[0] = make_float4(v[0], v[1], v[2], v[3]);
    dst[1] = make_float4(v[4], v[5], v[6], v[7]);
    dst[2] = make_float4(v[8], v[9], v[10], v[11]);
    dst[3] = make_float4(v[12], v[13], v[14], v[15]);
}

__global__ __launch_bounds__(THREADS) void cconv_main(
    const float* __restrict__ input, const float* __restrict__ pos,
    const float* __restrict__ W, const float* __restrict__ feat,
    float* __restrict__ out, int use_feat)
{
    // each wave (point) touches only its own LDS region; same-wave DS ops are
    // ordered -> no __syncthreads, waves fully decoupled.
    __shared__ __align__(16) float rec[PPB * GSTRIDE];

    const int tid = threadIdx.x;
    const int wv = tid >> 6;            // point-in-block (one wave per point)
    const int lane = tid & 63;
    const int sg = lane >> 4;           // sub-group 0..3
    const int lig = lane & 15;          // channel lane within sub-group
    const int pt = blockIdx.x * PPB + wv;
    const int b = pt >> 13;             // / kN

    const float px = pos[pt * 3 + 0];
    const float py = pos[pt * 3 + 1];
    const float pz = pos[pt * 3 + 2];
    const int bx = (int)floorf(px * 64.f);
    const int by = (int)floorf(py * 64.f);
    const int bz = (int)floorf(pz * 64.f);

    float* grec = rec + wv * GSTRIDE;
    int* iflats = reinterpret_cast<int*>(grec + MAXREC * SLOT);
    int nv = 0;

    // ---- pass 1a: validity over 216 candidates, full-wave ballot-compact ----
#pragma unroll
    for (int it = 0; it < 4; ++it) {
        int k = it * 64 + lane;
        bool valid = false;
        float rx = 0.f, ry = 0.f, rz = 0.f;
        int flat16 = 0;
        if (k < 216) {
            int a = k / 36;
            int r = k - a * 36;
            int b1 = r / 6;
            int c1 = r - b1 * 6;
            int g0 = bx + a - 2, g1 = by + b1 - 2, g2 = bz + c1 - 2;
            bool inb = (g0 >= 0) & (g0 < 64) & (g1 >= 0) & (g1 < 64) &
                       (g2 >= 0) & (g2 < 64);
            int q0 = min(max(g0, 0), 63);
            int q1 = min(max(g1, 0), 63);
            int q2 = min(max(g2, 0), 63);
            flat16 = ((q0 * 64 + q1) * 64 + q2) << 4;   // pre-scaled by C=16
            // grid_pos[i] == i*DX exactly -> compute, don't load
            rx = __fsub_rn((float)q0 * kDX, px);
            ry = __fsub_rn((float)q1 * kDX, py);
            rz = __fsub_rn((float)q2 * kDX, pz);
            // forbid fma-contraction so the <= compare matches XLA mul-then-add
            float d2 = __fadd_rn(__fadd_rn(__fmul_rn(rx, rx), __fmul_rn(ry, ry)),
                                 __fmul_rn(rz, rz));
            valid = inb && (d2 <= kRad2);
        }
        unsigned long long ball = __ballot(valid);
        if (valid) {
            int slot = nv + __popcll(ball & ((1ull << lane) - 1ull));
            *reinterpret_cast<float4*>(grec + slot * SLOT) =
                make_float4(rx, ry, rz, 0.f);
            iflats[slot] = flat16;
        }
        nv += (int)__popcll(ball);
    }
    __builtin_amdgcn_wave_barrier();

    // ---- zero-pad so pass 2 runs branch-free with deep prefetch ----
    if (lane < 8 && nv + lane < MAXREC) {
        float4 z = make_float4(0.f, 0.f, 0.f, 0.f);
        float4* zp = reinterpret_cast<float4*>(grec + (nv + lane) * SLOT);
        zp[0] = z; zp[1] = z; zp[2] = z;
    }
    if (lane < 24 && nv + lane < NFLAT) iflats[nv + lane] = 0;
    __builtin_amdgcn_wave_barrier();

    // ---- prime the 4-deep feature-gather pipeline (latency hides under pass 1b) ----
    const float* fbp = use_feat ? (feat + (size_t)b * kG * 16)
                                : (input + (size_t)b * 16 * kG);
    int fl0 = iflats[sg];
    int fl1 = iflats[sg + 4];
    int fl2 = iflats[sg + 8];
    int fl3 = iflats[sg + 12];
    float f0 = use_feat ? fbp[(size_t)fl0 + lig] : fbp[(size_t)lig * kG + (fl0 >> 4)];
    float f1 = use_feat ? fbp[(size_t)fl1 + lig] : fbp[(size_t)lig * kG + (fl1 >> 4)];
    float f2 = use_feat ? fbp[(size_t)fl2 + lig] : fbp[(size_t)lig * kG + (fl2 >> 4)];
    float f3 = use_feat ? fbp[(size_t)fl3 + lig] : fbp[(size_t)lig * kG + (fl3 >> 4)];

    // ---- pass 1b: mapping + hat weights -> 9 xy-products + wz0,wz1 ----
    for (int s = lane; s < nv; s += 64) {
        float* rp = grec + s * SLOT;
        float4 rc = *reinterpret_cast<const float4*>(rp);
        float ux = rc.x * kInvRad, uy = rc.y * kInvRad, uz = rc.z * kInvRad;

        // sphere -> cylinder (branch-free, HW rcp/rsq/sqrt: ~1ulp)
        float xx = ux * ux, yy = uy * uy, zz = uz * uz;
        float xy2 = xx + yy;
        float sq = xy2 + zz;
        float nrm = __builtin_amdgcn_sqrtf(fmaxf(sq, kEps));
        bool cap = (1.25f * zz > xy2);
        float scap = __builtin_amdgcn_sqrtf(3.f * nrm) *
                     __builtin_amdgcn_rsqf(nrm + fabsf(uz) + kEps);
        float sside = nrm * __builtin_amdgcn_rsqf(fmaxf(xy2, kEps));
        float sc = cap ? scap : sside;
        float xc = ux * sc, yc = uy * sc;
        float zc = cap ? sgnf(uz) * nrm : 1.5f * uz;
        if (sq <= kEps) { xc = 0.f; yc = 0.f; zc = 0.f; }

        // cylinder -> cube (single atan poly path)
        float xy2b = xc * xc + yc * yc;
        float nxy = __builtin_amdgcn_sqrtf(fmaxf(xy2b, kEps));
        bool xdom = (fabsf(yc) <= fabsf(xc));
        float num = xdom ? yc : xc;
        float den = xdom ? xc : yc;
        float dsafe = (fabsf(den) > kEps) ? den : 1.0f;
        float r = num * __builtin_amdgcn_rcpf(dsafe);     // |r| <= 1
        float r2 = r * r;
        float at = -0.01172120f;
        at = at * r2 + 0.05265332f;
        at = at * r2 - 0.11643287f;
        at = at * r2 + 0.19354346f;
        at = at * r2 - 0.33262347f;
        at = at * r2 + 0.99997726f;
        at = at * r;                                      // ~atan(r), err ~1e-5
        float tt = sgnf(den) * nxy;
        float g = tt * kFourOverPi * at;
        float xo = xdom ? tt : g;
        float yo = xdom ? g : tt;
        if (xy2b <= kEps) { xo = 0.f; yo = 0.f; }
        float zo = zc;

        // hat weights: c = clamp(v+1, 0, 2) (== ref's (v*0.5+0.5)*2 exactly)
        float tx = fminf(fmaxf(xo + 1.f, 0.f), 2.f) - 1.f;
        float ty = fminf(fmaxf(yo + 1.f, 0.f), 2.f) - 1.f;
        float tz = fminf(fmaxf(zo + 1.f, 0.f), 2.f) - 1.f;
        float wx0 = fmaxf(0.f, -tx), wx1 = 1.f - fabsf(tx), wx2 = fmaxf(0.f, tx);
        float wy0 = fmaxf(0.f, -ty), wy1 = 1.f - fabsf(ty), wy2 = fmaxf(0.f, ty);
        float wz0 = fmaxf(0.f, -tz), wz1 = 1.f - fabsf(tz);
        // wz2 reconstructed in pass 2 as (1-wz0)-wz1 (bit-exact vs ref)

        float4* rp4 = reinterpret_cast<float4*>(rp);
        rp4[0] = make_float4(wx0 * wy0, wx0 * wy1, wx0 * wy2, wx1 * wy0);
        rp4[1] = make_float4(wx1 * wy1, wx1 * wy2, wx2 * wy0, wx2 * wy1);
        rp4[2] = make_float4(wx2 * wy2, wz0, wz1, 0.f);
    }
    __builtin_amdgcn_wave_barrier();

    // ---- pass 2: sub-group sg takes records sg, sg+4, ...; 4 gathers in flight ----
    float acc[28];
#pragma unroll
    for (int t = 0; t < 28; ++t) acc[t] = 0.f;

    const int nvp = (nv + 3) & ~3;
    const float* rp = grec + sg * SLOT;
    float4 F0 = reinterpret_cast<const float4*>(rp)[0];
    float4 F1 = reinterpret_cast<const float4*>(rp)[1];
    float4 F2 = reinterpret_cast<const float4*>(rp)[2];

    for (int s = sg; s < nvp; s += 4) {
        // prefetch next record (LDS) + feature 4 records ahead (global)
        const float* rpn = rp + 4 * SLOT;
        float4 G0 = reinterpret_cast<const float4*>(rpn)[0];
        float4 G1 = reinterpret_cast<const float4*>(rpn)[1];
        float4 G2 = reinterpret_cast<const float4*>(rpn)[2];
        int fln = iflats[s + 16];
        float fnew = use_feat ? fbp[(size_t)fln + lig]
                              : fbp[(size_t)lig * kG + (fln >> 4)];

        float wz2 = (1.f - F2.y) - F2.z;
        float m0 = F2.y * f0, m1 = F2.z * f0, m2 = wz2 * f0;
        acc[0]  += F0.x * m0; acc[1]  += F0.x * m1; acc[2]  += F0.x * m2;
        acc[3]  += F0.y * m0; acc[4]  += F0.y * m1; acc[5]  += F0.y * m2;
        acc[6]  += F0.z * m0; acc[7]  += F0.z * m1; acc[8]  += F0.z * m2;
        acc[9]  += F0.w * m0; acc[10] += F0.w * m1; acc[11] += F0.w * m2;
        acc[12] += F1.x * m0; acc[13] += F1.x * m1; acc[14] += F1.x * m2;
        acc[15] += F1.y * m0; acc[16] += F1.y * m1; acc[17] += F1.y * m2;
        acc[18] += F1.z * m0; acc[19] += F1.z * m1; acc[20] += F1.z * m2;
        acc[21] += F1.w * m0; acc[22] += F1.w * m1; acc[23] += F1.w * m2;
        acc[24] += F2.x * m0; acc[25] += F2.x * m1; acc[26] += F2.x * m2;

        f0 = f1; f1 = f2; f2 = f3; f3 = fnew;            // static rotation
        F0 = G0; F1 = G1; F2 = G2; rp = rpn;
    }

    // ---- fold-reduce acc over sub-groups: sg ends with taps [7sg, 7sg+7) ----
    const bool hi32 = (lane >= 32);
    float kp[14];
#pragma unroll
    for (int j = 0; j < 14; ++j) {
        float send = hi32 ? acc[j] : acc[14 + j];
        float recv = __shfl_xor(send, 32);
        kp[j] = (hi32 ? acc[14 + j] : acc[j]) + recv;
    }
    const bool hi16 = (lane & 16) != 0;
    float kk[7];
#pragma unroll
    for (int j = 0; j < 7; ++j) {
        float send = hi16 ? kp[j] : kp[7 + j];
        float recv = __shfl_xor(send, 16);
        kk[j] = (hi16 ? kp[7 + j] : kp[j]) + recv;
    }

    // ---- pass 3: taps t = 7sg+j; partial[d] += kk[j] * W[t][lig][d] ----
    float partial[16];
#pragma unroll
    for (int d = 0; d < 16; ++d) partial[d] = 0.f;
    const float* wbase = W + (sg * 7) * 256 + lig * 16;
#pragma unroll
    for (int j = 0; j < 7; ++j) {
        if (sg * 7 + j < 27) {          // sg3,j6 is the pad tap
            const float4* wr = reinterpret_cast<const float4*>(wbase + j * 256);
            float4 a0 = wr[0], a1 = wr[1], a2 = wr[2], a3 = wr[3];
            float at_ = kk[j];
            partial[0]  += at_ * a0.x; partial[1]  += at_ * a0.y;
            partial[2]  += at_ * a0.z; partial[3]  += at_ * a0.w;
            partial[4]  += at_ * a1.x; partial[5]  += at_ * a1.y;
            partial[6]  += at_ * a1.z; partial[7]  += at_ * a1.w;
            partial[8]  += at_ * a2.x; partial[9]  += at_ * a2.y;
            partial[10] += at_ * a2.z; partial[11] += at_ * a2.w;
            partial[12] += at_ * a3.x; partial[13] += at_ * a3.y;
            partial[14] += at_ * a3.z; partial[15] += at_ * a3.w;
        }
    }

    // ---- fold-reduce 16 partials across the 16-lane group: lane lig ends with d=lig ----
#pragma unroll
    for (int half = 8; half >= 1; half >>= 1) {
        bool up = (lig & half) != 0;
#pragma unroll
        for (int j = 0; j < half; ++j) {
            float send = up ? partial[j] : partial[j + half];
            float recv = __shfl_xor(send, half);
            partial[j] = (up ? partial[j + half] : partial[j]) + recv;
        }
    }
    float res = partial[0];
    res += __shfl_xor(res, 16);
    res += __shfl_xor(res, 32);
    res = res / fmaxf((float)nv, 1.f);
    if (lane < 16) out[(size_t)pt * 16 + lig] = res;
}

extern "C" void kernel_launch(void* const* d_in, const int* in_sizes, int n_in,
                              void* d_out, int out_size, void* d_ws, size_t ws_size,
                              hipStream_t stream) {
    const float* input = (const float*)d_in[0];   // [2,16,64,64,64]
    const float* pos   = (const float*)d_in[1];   // [2,8192,3]
    const float* W     = (const float*)d_in[2];   // [3,3,3,16,16]
    // d_in[3] grid_pos unused: grid_pos[i] == i*DX exactly
    float* out  = (float*)d_out;
    float* feat = (float*)d_ws;

    const size_t feat_bytes = (size_t)kB * kG * 16 * sizeof(float);
    int use_feat = (d_ws != nullptr && ws_size >= feat_bytes) ? 1 : 0;

    if (use_feat) {
        transpose_feat_k<<<(kB * kG + 255) / 256, 256, 0, stream>>>(input, feat);
    }
    cconv_main<<<kPts / PPB, THREADS, 0, stream>>>(input, pos, W, feat, out, use_feat);
}

// Round 6
// 74.836 us; speedup vs baseline: 1.1230x; 1.0639x over previous
//
#include <hip/hip_runtime.h>
#include <cstdint>

typedef float v2f __attribute__((ext_vector_type(2)));

namespace {
constexpr int kG = 262144;                    // 64^3 cells
constexpr int kB = 2;
constexpr int kN = 8192;
constexpr int kPts = kB * kN;                 // 16384 points
constexpr float kDX = 1.0f / 64.0f;
constexpr float kRad2 = 0.00152587890625f;    // (2.5/64)^2, exact
constexpr float kInvRad = 25.6f;              // 1/RADIUS
constexpr float kEps = 1e-12f;
constexpr float kFourOverPi = 1.27323954473516268615f;

constexpr int PPB = 4;                        // points per block (1 wave each)
constexpr int THREADS = PPB * 64;             // 256
constexpr int MAXREC = 96;                    // nv<=81, padded to multiple of 16
constexpr int SLOT = 12;                      // floats/record: 48B stride cycles banks
constexpr int NFLAT = 96;                     // compact flat-index array
constexpr int GSTRIDE = MAXREC * SLOT + NFLAT; // 1248 floats per point region
}

__device__ __forceinline__ float sgnf(float v) {
    return (v > 0.f) ? 1.f : ((v < 0.f) ? -1.f : 0.f);
}

// ---- transpose [B][C][G] -> [B][G][C] so per-cell channel gathers are one 64B line ----
__global__ __launch_bounds__(256) void transpose_feat_k(const float* __restrict__ in,
                                                        float* __restrict__ feat) {
    int idx = blockIdx.x * 256 + threadIdx.x;      // over B*G
    if (idx >= kB * kG) return;
    int b = idx >> 18;
    int g = idx & (kG - 1);
    float v[16];
#pragma unroll
    for (int c = 0; c < 16; ++c) v[c] = in[((size_t)(b * 16 + c)) * kG + g];
    float4* dst = reinterpret_cast<float4*>(feat + (size_t)idx * 16);
    dst[0] = make_float4(v[0], v[1], v[2], v[3]);
    dst[1] = make_float4(v[4], v[5], v[6], v[7]);
    dst[2] = make_float4(v[8], v[9], v[10], v[11]);
    dst[3] = make_float4(v[12], v[13], v[14], v[15]);
}

__global__ __launch_bounds__(THREADS) void cconv_main(
    const float* __restrict__ input, const float* __restrict__ pos,
    const float* __restrict__ W, const float* __restrict__ feat,
    float* __restrict__ out, int use_feat)
{
    // each wave (point) touches only its own LDS region; same-wave DS ops are
    // ordered -> no __syncthreads, waves fully decoupled.
    __shared__ __align__(16) float rec[PPB * GSTRIDE];   // 19,968 B

    const int tid = threadIdx.x;
    const int wv = tid >> 6;            // point-in-block (one wave per point)
    const int lane = tid & 63;
    const int sg = lane >> 4;           // sub-group 0..3
    const int lig = lane & 15;          // channel lane within sub-group
    const int pt = blockIdx.x * PPB + wv;
    const int b = pt >> 13;             // / kN

    const float px = pos[pt * 3 + 0];
    const float py = pos[pt * 3 + 1];
    const float pz = pos[pt * 3 + 2];
    const int bx = (int)floorf(px * 64.f);
    const int by = (int)floorf(py * 64.f);
    const int bz = (int)floorf(pz * 64.f);

    float* grec = rec + wv * GSTRIDE;
    int* iflats = reinterpret_cast<int*>(grec + MAXREC * SLOT);
    int nv = 0;

    // ---- pass 1a: validity over 216 candidates, full-wave ballot-compact ----
#pragma unroll
    for (int it = 0; it < 4; ++it) {
        int k = it * 64 + lane;
        bool valid = false;
        float rx = 0.f, ry = 0.f, rz = 0.f;
        int flat16 = 0;
        if (k < 216) {
            int a = k / 36;
            int r = k - a * 36;
            int b1 = r / 6;
            int c1 = r - b1 * 6;
            int g0 = bx + a - 2, g1 = by + b1 - 2, g2 = bz + c1 - 2;
            bool inb = (g0 >= 0) & (g0 < 64) & (g1 >= 0) & (g1 < 64) &
                       (g2 >= 0) & (g2 < 64);
            int q0 = min(max(g0, 0), 63);
            int q1 = min(max(g1, 0), 63);
            int q2 = min(max(g2, 0), 63);
            flat16 = ((q0 * 64 + q1) * 64 + q2) << 4;   // pre-scaled by C=16
            // grid_pos[i] == i*DX exactly -> compute, don't load
            rx = __fsub_rn((float)q0 * kDX, px);
            ry = __fsub_rn((float)q1 * kDX, py);
            rz = __fsub_rn((float)q2 * kDX, pz);
            // forbid fma-contraction so the <= compare matches XLA mul-then-add
            float d2 = __fadd_rn(__fadd_rn(__fmul_rn(rx, rx), __fmul_rn(ry, ry)),
                                 __fmul_rn(rz, rz));
            valid = inb && (d2 <= kRad2);
        }
        unsigned long long ball = __ballot(valid);
        if (valid) {
            int slot = nv + __popcll(ball & ((1ull << lane) - 1ull));
            *reinterpret_cast<float4*>(grec + slot * SLOT) =
                make_float4(rx, ry, rz, 0.f);
            iflats[slot] = flat16;
        }
        nv += (int)__popcll(ball);
    }
    __builtin_amdgcn_wave_barrier();

    // ---- zero-pad records + flats up to 96 (branch-free padded pass 2) ----
    for (int z = nv + lane; z < MAXREC; z += 64) {
        float4 zf = make_float4(0.f, 0.f, 0.f, 0.f);
        float4* zp = reinterpret_cast<float4*>(grec + z * SLOT);
        zp[0] = zf; zp[1] = zf; zp[2] = zf;    // all xy-products zero -> no contribution
        iflats[z] = 0;
    }
    __builtin_amdgcn_wave_barrier();

    // ---- prime the 2-bank (32-record-deep) feature gather pipeline ----
    const float* fbp = use_feat ? (feat + (size_t)b * kG * 16)
                                : (input + (size_t)b * 16 * kG);
#define LDF(IDX) (use_feat ? fbp[(size_t)iflats[(IDX)] + lig]                 \
                           : fbp[(size_t)lig * kG + (iflats[(IDX)] >> 4)])
    float fa0 = LDF(sg),      fa1 = LDF(sg + 4);
    float fa2 = LDF(sg + 8),  fa3 = LDF(sg + 12);
    float fb0 = LDF(sg + 16), fb1 = LDF(sg + 20);
    float fb2 = LDF(sg + 24), fb3 = LDF(sg + 28);

    // ---- pass 1b: mapping + hat weights -> 9 xy-products + wz0,wz1 ----
    for (int s = lane; s < nv; s += 64) {
        float* rp = grec + s * SLOT;
        float4 rc = *reinterpret_cast<const float4*>(rp);
        float ux = rc.x * kInvRad, uy = rc.y * kInvRad, uz = rc.z * kInvRad;

        // sphere -> cylinder (branch-free, HW rcp/rsq/sqrt: ~1ulp)
        float xx = ux * ux, yy = uy * uy, zz = uz * uz;
        float xy2 = xx + yy;
        float sq = xy2 + zz;
        float nrm = __builtin_amdgcn_sqrtf(fmaxf(sq, kEps));
        bool cap = (1.25f * zz > xy2);
        float scap = __builtin_amdgcn_sqrtf(3.f * nrm) *
                     __builtin_amdgcn_rsqf(nrm + fabsf(uz) + kEps);
        float sside = nrm * __builtin_amdgcn_rsqf(fmaxf(xy2, kEps));
        float sc = cap ? scap : sside;
        float xc = ux * sc, yc = uy * sc;
        float zc = cap ? sgnf(uz) * nrm : 1.5f * uz;
        if (sq <= kEps) { xc = 0.f; yc = 0.f; zc = 0.f; }

        // cylinder -> cube (single atan poly path)
        float xy2b = xc * xc + yc * yc;
        float nxy = __builtin_amdgcn_sqrtf(fmaxf(xy2b, kEps));
        bool xdom = (fabsf(yc) <= fabsf(xc));
        float num = xdom ? yc : xc;
        float den = xdom ? xc : yc;
        float dsafe = (fabsf(den) > kEps) ? den : 1.0f;
        float r = num * __builtin_amdgcn_rcpf(dsafe);     // |r| <= 1
        float r2 = r * r;
        float at = -0.01172120f;
        at = at * r2 + 0.05265332f;
        at = at * r2 - 0.11643287f;
        at = at * r2 + 0.19354346f;
        at = at * r2 - 0.33262347f;
        at = at * r2 + 0.99997726f;
        at = at * r;                                      // ~atan(r), err ~1e-5
        float tt = sgnf(den) * nxy;
        float g = tt * kFourOverPi * at;
        float xo = xdom ? tt : g;
        float yo = xdom ? g : tt;
        if (xy2b <= kEps) { xo = 0.f; yo = 0.f; }
        float zo = zc;

        // hat weights: c = clamp(v+1, 0, 2) (== ref's (v*0.5+0.5)*2 exactly)
        float tx = fminf(fmaxf(xo + 1.f, 0.f), 2.f) - 1.f;
        float ty = fminf(fmaxf(yo + 1.f, 0.f), 2.f) - 1.f;
        float tz = fminf(fmaxf(zo + 1.f, 0.f), 2.f) - 1.f;
        float wx0 = fmaxf(0.f, -tx), wx1 = 1.f - fabsf(tx), wx2 = fmaxf(0.f, tx);
        float wy0 = fmaxf(0.f, -ty), wy1 = 1.f - fabsf(ty), wy2 = fmaxf(0.f, ty);
        float wz0 = fmaxf(0.f, -tz), wz1 = 1.f - fabsf(tz);
        // wz2 reconstructed in pass 2 as (1-wz0)-wz1

        float4* rp4 = reinterpret_cast<float4*>(rp);
        rp4[0] = make_float4(wx0 * wy0, wx0 * wy1, wx0 * wy2, wx1 * wy0);
        rp4[1] = make_float4(wx1 * wy1, wx1 * wy2, wx2 * wy0, wx2 * wy1);
        rp4[2] = make_float4(wx2 * wy2, wz0, wz1, 0.f);
    }
    __builtin_amdgcn_wave_barrier();

    // ---- pass 2: fully unrolled 6 bodies, 4 records/body/sub-group, pk FMAs ----
    v2f az0_01 = {0.f, 0.f}, az1_01 = {0.f, 0.f}, az2_01 = {0.f, 0.f};
    v2f az0_23 = {0.f, 0.f}, az1_23 = {0.f, 0.f}, az2_23 = {0.f, 0.f};
    v2f az0_45 = {0.f, 0.f}, az1_45 = {0.f, 0.f}, az2_45 = {0.f, 0.f};
    v2f az0_67 = {0.f, 0.f}, az1_67 = {0.f, 0.f}, az2_67 = {0.f, 0.f};
    float a8_0 = 0.f, a8_1 = 0.f, a8_2 = 0.f;

    const int nvp16 = (nv + 15) & ~15;
    const int M = nvp16 >> 4;           // 1..6 macro-bodies (wave-uniform)

#define REC_FMA(S, FV)                                                        \
  {                                                                           \
    const float4* rp4_ = reinterpret_cast<const float4*>(grec + (S) * SLOT);  \
    float4 Wa = rp4_[0], Wb = rp4_[1], Wc = rp4_[2];                          \
    float m0 = Wc.y * (FV), m1 = Wc.z * (FV);                                 \
    float m2 = ((1.f - Wc.y) - Wc.z) * (FV);                                  \
    v2f mz0 = {m0, m0}, mz1 = {m1, m1}, mz2 = {m2, m2};                       \
    v2f p01 = {Wa.x, Wa.y}, p23 = {Wa.z, Wa.w};                               \
    v2f p45 = {Wb.x, Wb.y}, p67 = {Wb.z, Wb.w};                               \
    az0_01 = __builtin_elementwise_fma(p01, mz0, az0_01);                     \
    az1_01 = __builtin_elementwise_fma(p01, mz1, az1_01);                     \
    az2_01 = __builtin_elementwise_fma(p01, mz2, az2_01);                     \
    az0_23 = __builtin_elementwise_fma(p23, mz0, az0_23);                     \
    az1_23 = __builtin_elementwise_fma(p23, mz1, az1_23);                     \
    az2_23 = __builtin_elementwise_fma(p23, mz2, az2_23);                     \
    az0_45 = __builtin_elementwise_fma(p45, mz0, az0_45);                     \
    az1_45 = __builtin_elementwise_fma(p45, mz1, az1_45);                     \
    az2_45 = __builtin_elementwise_fma(p45, mz2, az2_45);                     \
    az0_67 = __builtin_elementwise_fma(p67, mz0, az0_67);                     \
    az1_67 = __builtin_elementwise_fma(p67, mz1, az1_67);                     \
    az2_67 = __builtin_elementwise_fma(p67, mz2, az2_67);                     \
    a8_0 = __builtin_fmaf(Wc.x, m0, a8_0);                                    \
    a8_1 = __builtin_fmaf(Wc.x, m1, a8_1);                                    \
    a8_2 = __builtin_fmaf(Wc.x, m2, a8_2);                                    \
  }

#define P2BODY(KK, F0_, F1_, F2_, F3_)                                        \
  {                                                                           \
    const int rb_ = (KK) * 16 + sg;                                           \
    float nf0_ = 0.f, nf1_ = 0.f, nf2_ = 0.f, nf3_ = 0.f;                     \
    const bool dol_ = (M > (KK) + 2);                                         \
    if (dol_) {                                                               \
      int q0_ = iflats[rb_ + 32], q1_ = iflats[rb_ + 36],                     \
          q2_ = iflats[rb_ + 40], q3_ = iflats[rb_ + 44];                     \
      if (use_feat) {                                                         \
        nf0_ = fbp[(size_t)q0_ + lig]; nf1_ = fbp[(size_t)q1_ + lig];         \
        nf2_ = fbp[(size_t)q2_ + lig]; nf3_ = fbp[(size_t)q3_ + lig];         \
      } else {                                                                \
        nf0_ = fbp[(size_t)lig * kG + (q0_ >> 4)];                            \
        nf1_ = fbp[(size_t)lig * kG + (q1_ >> 4)];                            \
        nf2_ = fbp[(size_t)lig * kG + (q2_ >> 4)];                            \
        nf3_ = fbp[(size_t)lig * kG + (q3_ >> 4)];                            \
      }                                                                       \
    }                                                                         \
    REC_FMA(rb_,      F0_); REC_FMA(rb_ + 4,  F1_);                           \
    REC_FMA(rb_ + 8,  F2_); REC_FMA(rb_ + 12, F3_);                           \
    if (dol_) { F0_ = nf0_; F1_ = nf1_; F2_ = nf2_; F3_ = nf3_; }             \
  }

    if (M > 0) P2BODY(0, fa0, fa1, fa2, fa3)
    if (M > 1) P2BODY(1, fb0, fb1, fb2, fb3)
    if (M > 2) P2BODY(2, fa0, fa1, fa2, fa3)
    if (M > 3) P2BODY(3, fb0, fb1, fb2, fb3)
    if (M > 4) P2BODY(4, fa0, fa1, fa2, fa3)
    if (M > 5) P2BODY(5, fb0, fb1, fb2, fb3)

    // ---- scatter acc into t = 3i+z order (register renames, zero cost) ----
    float acc[28] = {
        az0_01.x, az1_01.x, az2_01.x,   // i=0
        az0_01.y, az1_01.y, az2_01.y,   // i=1
        az0_23.x, az1_23.x, az2_23.x,   // i=2
        az0_23.y, az1_23.y, az2_23.y,   // i=3
        az0_45.x, az1_45.x, az2_45.x,   // i=4
        az0_45.y, az1_45.y, az2_45.y,   // i=5
        az0_67.x, az1_67.x, az2_67.x,   // i=6
        az0_67.y, az1_67.y, az2_67.y,   // i=7
        a8_0,     a8_1,     a8_2,       // i=8
        0.f                              // pad tap 27
    };

    // ---- fold-reduce acc over sub-groups (R4-proven shfl code) ----
    const bool hi32 = (lane >= 32);
    float kp[14];
#pragma unroll
    for (int j = 0; j < 14; ++j) {
        float send = hi32 ? acc[j] : acc[14 + j];
        float recv = __shfl_xor(send, 32);
        kp[j] = (hi32 ? acc[14 + j] : acc[j]) + recv;
    }
    const bool hi16 = (lane & 16) != 0;
    float kk[7];
#pragma unroll
    for (int j = 0; j < 7; ++j) {
        float send = hi16 ? kp[j] : kp[7 + j];
        float recv = __shfl_xor(send, 16);
        kk[j] = (hi16 ? kp[7 + j] : kp[j]) + recv;
    }

    // ---- pass 3: taps t = 7sg+j; partial[d] += kk[j] * W[t][lig][d] ----
    float partial[16];
#pragma unroll
    for (int d = 0; d < 16; ++d) partial[d] = 0.f;
    const float* wbase = W + (sg * 7) * 256 + lig * 16;
#pragma unroll
    for (int j = 0; j < 7; ++j) {
        if (sg * 7 + j < 27) {          // sg3,j6 is the pad tap
            const float4* wr = reinterpret_cast<const float4*>(wbase + j * 256);
            float4 a0 = wr[0], a1 = wr[1], a2 = wr[2], a3 = wr[3];
            float at_ = kk[j];
            partial[0]  += at_ * a0.x; partial[1]  += at_ * a0.y;
            partial[2]  += at_ * a0.z; partial[3]  += at_ * a0.w;
            partial[4]  += at_ * a1.x; partial[5]  += at_ * a1.y;
            partial[6]  += at_ * a1.z; partial[7]  += at_ * a1.w;
            partial[8]  += at_ * a2.x; partial[9]  += at_ * a2.y;
            partial[10] += at_ * a2.z; partial[11] += at_ * a2.w;
            partial[12] += at_ * a3.x; partial[13] += at_ * a3.y;
            partial[14] += at_ * a3.z; partial[15] += at_ * a3.w;
        }
    }

    // ---- fold-reduce 16 partials across the 16-lane group (R4-proven) ----
#pragma unroll
    for (int half = 8; half >= 1; half >>= 1) {
        bool up = (lig & half) != 0;
#pragma unroll
        for (int j = 0; j < half; ++j) {
            float send = up ? partial[j] : partial[j + half];
            float recv = __shfl_xor(send, half);
            partial[j] = (up ? partial[j + half] : partial[j]) + recv;
        }
    }
    float res = partial[0];
    res += __shfl_xor(res, 16);
    res += __shfl_xor(res, 32);
    res = res / fmaxf((float)nv, 1.f);
    if (lane < 16) out[(size_t)pt * 16 + lig] = res;
#undef LDF
#undef REC_FMA
#undef P2BODY
}

extern "C" void kernel_launch(void* const* d_in, const int* in_sizes, int n_in,
                              void* d_out, int out_size, void* d_ws, size_t ws_size,
                              hipStream_t stream) {
    const float* input = (const float*)d_in[0];   // [2,16,64,64,64]
    const float* pos   = (const float*)d_in[1];   // [2,8192,3]
    const float* W     = (const float*)d_in[2];   // [3,3,3,16,16]
    // d_in[3] grid_pos unused: grid_pos[i] == i*DX exactly
    float* out  = (float*)d_out;
    float* feat = (float*)d_ws;

    const size_t feat_bytes = (size_t)kB * kG * 16 * sizeof(float);
    int use_feat = (d_ws != nullptr && ws_size >= feat_bytes) ? 1 : 0;

    if (use_feat) {
        transpose_feat_k<<<(kB * kG + 255) / 256, 256, 0, stream>>>(input, feat);
    }
    cconv_main<<<kPts / PPB, THREADS, 0, stream>>>(input, pos, W, feat, out, use_feat);
}